// Round 2
// baseline (192.134 us; speedup 1.0000x reference)
//
#include <hip/hip_runtime.h>
#include <math.h>

// SOR defense: B=4, K=8192, 3D points. k-NN with k=2 (3 smallest incl. self).
// Outputs: masked_pc [4,8192,3] (98304 floats) then mask [4,8192] (32768 floats).

constexpr int B = 4;
constexpr int K = 8192;
constexpr int QPB = 256;      // queries per block (= threads)

#define BIG 3.0e38f

// Branchless insert of d into sorted top-3 (d0<=d1<=d2 smallest seen).
// Executing with d >= d2 leaves state exactly unchanged, so guarding with
// "any lane has d < d2" is bit-identical to the unconditional version.
#define INSERT3(d, d0, d1, d2)          \
  do {                                  \
    float e_ = fminf((d), (d2));        \
    (d2) = fmaxf((d1), e_);             \
    float m_ = fminf((d1), e_);         \
    (d1) = fmaxf((d0), m_);             \
    (d0) = fminf((d0), m_);             \
  } while (0)

template <int CHUNK>
__global__ __launch_bounds__(QPB) void knn_part_kernel(
    const float* __restrict__ x, float* __restrict__ part) {
  constexpr int NCH = K / CHUNK;
  const int bid = blockIdx.x;
  const int chunk = bid % NCH;
  const int rest  = bid / NCH;
  const int kc    = rest % (K / QPB);
  const int b     = rest / (K / QPB);
  const int tid = threadIdx.x;
  const int k   = kc * QPB + tid;

  const float* xb = x + (size_t)b * K * 3;

  // Query point + its squared norm (same op order as reference)
  const float qx = xb[(size_t)k * 3 + 0];
  const float qy = xb[(size_t)k * 3 + 1];
  const float qz = xb[(size_t)k * 3 + 2];
  const float xxk = (qx * qx + qy * qy) + qz * qz;

  __shared__ float4 s[CHUNK];  // (x, y, z, ||p||^2)

  const int jbase = chunk * CHUNK;
  for (int i = tid; i < CHUNK; i += QPB) {
    const float px = xb[(size_t)(jbase + i) * 3 + 0];
    const float py = xb[(size_t)(jbase + i) * 3 + 1];
    const float pz = xb[(size_t)(jbase + i) * 3 + 2];
    s[i] = make_float4(px, py, pz, (px * px + py * py) + pz * pz);
  }
  __syncthreads();

  float d0 = BIG, d1 = BIG, d2 = BIG;
#pragma unroll 8
  for (int j = 0; j < CHUNK; ++j) {
    const float4 p = s[j];
    const float dot = (qx * p.x + qy * p.y) + qz * p.z;
    const float d = (xxk - 2.0f * dot) + p.w;
    if (__any(d < d2)) {
      INSERT3(d, d0, d1, d2);
    }
  }

  float* pp = part + ((size_t)(b * K + k) * NCH + chunk) * 3;
  pp[0] = d0;
  pp[1] = d1;
  pp[2] = d2;
}

__global__ __launch_bounds__(1024) void finalize_kernel(
    const float* __restrict__ x, const float* __restrict__ part,
    float* __restrict__ out, int nch) {
  const int b = blockIdx.x;
  const int tid = threadIdx.x;
  constexpr int PER = K / 1024;  // 8

  float val[PER];
  double s = 0.0, s2 = 0.0;

  for (int i = 0; i < PER; ++i) {
    const int k = i * 1024 + tid;
    const float* pp = part + (size_t)(b * K + k) * nch * 3;
    float d0 = BIG, d1 = BIG, d2 = BIG;
    for (int t = 0; t < nch * 3; ++t) {
      const float d = pp[t];
      INSERT3(d, d0, d1, d2);
    }
    // drop self (d0 ~ 0), mean of 2nd and 3rd smallest
    const float v = 0.5f * (d1 + d2);
    val[i] = v;
    s += (double)v;
    s2 += (double)v * (double)v;
  }

  // wave (64-lane) reduction
  for (int off = 32; off > 0; off >>= 1) {
    s  += __shfl_down(s, off, 64);
    s2 += __shfl_down(s2, off, 64);
  }

  __shared__ double rs[16], rs2[16];
  __shared__ float sthr;
  const int wave = tid >> 6;
  const int lane = tid & 63;
  if (lane == 0) { rs[wave] = s; rs2[wave] = s2; }
  __syncthreads();
  if (tid == 0) {
    double S = 0.0, S2 = 0.0;
    for (int w = 0; w < 16; ++w) { S += rs[w]; S2 += rs2[w]; }
    const double mean = S / (double)K;
    const double var  = (S2 - S * S / (double)K) / (double)(K - 1);
    const double thr  = mean + 1.1 * sqrt(var);
    sthr = (float)thr;
  }
  __syncthreads();

  const float thr = sthr;
  for (int i = 0; i < PER; ++i) {
    const int k = i * 1024 + tid;
    const float m = (val[i] <= thr) ? 1.0f : 0.0f;
    out[(size_t)B * K * 3 + (size_t)b * K + k] = m;
    const size_t base = (size_t)(b * K + k) * 3;
    out[base + 0] = x[base + 0] * m;
    out[base + 1] = x[base + 1] * m;
    out[base + 2] = x[base + 2] * m;
  }
}

extern "C" void kernel_launch(void* const* d_in, const int* in_sizes, int n_in,
                              void* d_out, int out_size, void* d_ws, size_t ws_size,
                              hipStream_t stream) {
  const float* x = (const float*)d_in[0];
  float* out = (float*)d_out;
  float* part = (float*)d_ws;

  const size_t need8 = (size_t)B * K * 8 * 3 * sizeof(float);  // 3 MiB
  if (ws_size >= need8) {
    // 8-way j-split: 1024 blocks, 16 KiB LDS -> ~4 blocks/CU resident
    knn_part_kernel<K / 8><<<B * (K / QPB) * 8, QPB, 0, stream>>>(x, part);
    finalize_kernel<<<B, 1024, 0, stream>>>(x, part, out, 8);
  } else {
    // fallback: 2-way split (768 KiB partials, known to fit)
    knn_part_kernel<K / 2><<<B * (K / QPB) * 2, QPB, 0, stream>>>(x, part);
    finalize_kernel<<<B, 1024, 0, stream>>>(x, part, out, 2);
  }
}

// Round 3
// 94.089 us; speedup vs baseline: 2.0420x; 2.0420x over previous
//
#include <hip/hip_runtime.h>
#include <math.h>

// SOR defense: B=4, K=8192, 3D points. kNN k=2 (3 smallest incl. self).
// Outputs: masked_pc [4,8192,3] then mask [4,8192] (floats).

constexpr int B = 4;
constexpr int K = 8192;
constexpr int QPB = 256;   // threads per block
constexpr int QPT = 2;     // queries per thread
constexpr int QBLK = QPB * QPT;  // 512 queries per block

#define BIG 3.0e38f

// Branchless insert of d into sorted top-3 (d0<=d1<=d2 smallest seen).
#define INSERT3(d, d0, d1, d2)          \
  do {                                  \
    float e_ = fminf((d), (d2));        \
    (d2) = fmaxf((d1), e_);             \
    float m_ = fminf((d1), e_);         \
    (d1) = fmaxf((d0), m_);             \
    (d0) = fminf((d0), m_);             \
  } while (0)

template <int CHUNK>
__global__ __launch_bounds__(QPB) void knn_part_kernel(
    const float* __restrict__ x, float* __restrict__ part) {
  constexpr int NCH = K / CHUNK;
  const int bid   = blockIdx.x;
  const int chunk = bid % NCH;
  const int rest  = bid / NCH;
  const int kc    = rest % (K / QBLK);
  const int b     = rest / (K / QBLK);
  const int tid   = threadIdx.x;

  const float* xb = x + (size_t)b * K * 3;

  // Two queries per thread; same op order as reference for xx.
  float qx[QPT], qy[QPT], qz[QPT], qn[QPT];
  int kq[QPT];
#pragma unroll
  for (int q = 0; q < QPT; ++q) {
    const int k = kc * QBLK + q * QPB + tid;
    kq[q] = k;
    qx[q] = xb[(size_t)k * 3 + 0];
    qy[q] = xb[(size_t)k * 3 + 1];
    qz[q] = xb[(size_t)k * 3 + 2];
    qn[q] = (qx[q] * qx[q] + qy[q] * qy[q]) + qz[q] * qz[q];
  }

  __shared__ float4 s[CHUNK];  // (x, y, z, ||p||^2)
  const int jbase = chunk * CHUNK;
  for (int i = tid; i < CHUNK; i += QPB) {
    const float px = xb[(size_t)(jbase + i) * 3 + 0];
    const float py = xb[(size_t)(jbase + i) * 3 + 1];
    const float pz = xb[(size_t)(jbase + i) * 3 + 2];
    s[i] = make_float4(px, py, pz, (px * px + py * py) + pz * pz);
  }
  __syncthreads();

  // 4 independent top-3 chains: [query][j-parity]. Merged at the end;
  // the 3 smallest of the union is the same multiset as sequential insert.
  float e0[QPT][2], e1[QPT][2], e2[QPT][2];
#pragma unroll
  for (int q = 0; q < QPT; ++q)
#pragma unroll
    for (int p = 0; p < 2; ++p) { e0[q][p] = BIG; e1[q][p] = BIG; e2[q][p] = BIG; }

  for (int j = 0; j < CHUNK; j += 4) {
    float4 p[4];
#pragma unroll
    for (int u = 0; u < 4; ++u) p[u] = s[j + u];
#pragma unroll
    for (int u = 0; u < 4; ++u) {
      const int par = u & 1;
#pragma unroll
      for (int q = 0; q < QPT; ++q) {
        const float dot = (qx[q] * p[u].x + qy[q] * p[u].y) + qz[q] * p[u].z;
        const float d = (qn[q] - 2.0f * dot) + p[u].w;
        INSERT3(d, e0[q][par], e1[q][par], e2[q][par]);
      }
    }
  }

#pragma unroll
  for (int q = 0; q < QPT; ++q) {
    INSERT3(e0[q][1], e0[q][0], e1[q][0], e2[q][0]);
    INSERT3(e1[q][1], e0[q][0], e1[q][0], e2[q][0]);
    INSERT3(e2[q][1], e0[q][0], e1[q][0], e2[q][0]);
    float* pp = part + ((size_t)(b * K + kq[q]) * NCH + chunk) * 3;
    pp[0] = e0[q][0];
    pp[1] = e1[q][0];
    pp[2] = e2[q][0];
  }
}

// Stage 1: merge partials -> value[b,k]; per-block double sums.
template <int NCH>
__global__ __launch_bounds__(256) void sor_value_kernel(
    const float* __restrict__ part, float* __restrict__ value,
    double* __restrict__ bsum) {
  const int blk = blockIdx.x;        // b*32 + sub
  const int b   = blk >> 5;
  const int tid = threadIdx.x;
  const int k   = (blk & 31) * 256 + tid;

  const float* pp = part + (size_t)(b * K + k) * NCH * 3;
  float d0 = BIG, d1 = BIG, d2 = BIG;
#pragma unroll
  for (int t = 0; t < NCH * 3; ++t) {
    const float d = pp[t];
    INSERT3(d, d0, d1, d2);
  }
  const float v = 0.5f * (d1 + d2);  // drop self (d0), mean of 2 kNN
  value[b * K + k] = v;

  double s = (double)v, s2 = (double)v * (double)v;
  for (int off = 32; off > 0; off >>= 1) {
    s  += __shfl_down(s, off, 64);
    s2 += __shfl_down(s2, off, 64);
  }
  __shared__ double rs[4], rs2[4];
  const int wave = tid >> 6;
  if ((tid & 63) == 0) { rs[wave] = s; rs2[wave] = s2; }
  __syncthreads();
  if (tid == 0) {
    double S = 0.0, S2 = 0.0;
    for (int w = 0; w < 4; ++w) { S += rs[w]; S2 += rs2[w]; }  // fixed order
    bsum[blk * 2 + 0] = S;
    bsum[blk * 2 + 1] = S2;
  }
}

// Stage 2: threshold per batch (fixed order -> deterministic).
__global__ __launch_bounds__(64) void sor_thresh_kernel(
    const double* __restrict__ bsum, float* __restrict__ thr) {
  const int b = threadIdx.x;
  if (b < B) {
    double S = 0.0, S2 = 0.0;
    for (int w = 0; w < 32; ++w) {
      S  += bsum[(b * 32 + w) * 2 + 0];
      S2 += bsum[(b * 32 + w) * 2 + 1];
    }
    const double mean = S / (double)K;
    const double var  = (S2 - S * S / (double)K) / (double)(K - 1);
    thr[b] = (float)(mean + 1.1 * sqrt(var));
  }
}

// Stage 3: apply mask.
__global__ __launch_bounds__(256) void sor_mask_kernel(
    const float* __restrict__ x, const float* __restrict__ value,
    const float* __restrict__ thr, float* __restrict__ out) {
  const int g = blockIdx.x * 256 + threadIdx.x;  // b*K + k
  const int b = g / K;
  const float m = (value[g] <= thr[b]) ? 1.0f : 0.0f;
  out[(size_t)B * K * 3 + g] = m;
  const size_t base = (size_t)g * 3;
  out[base + 0] = x[base + 0] * m;
  out[base + 1] = x[base + 1] * m;
  out[base + 2] = x[base + 2] * m;
}

template <int NCH>
static void run(const float* x, float* out, char* ws, hipStream_t stream) {
  float* part = (float*)ws;
  size_t off = (size_t)B * K * NCH * 3 * sizeof(float);
  float* value = (float*)(ws + off);
  off += (size_t)B * K * sizeof(float);
  off = (off + 7) & ~(size_t)7;
  double* bsum = (double*)(ws + off);
  off += (size_t)B * 32 * 2 * sizeof(double);
  float* thr = (float*)(ws + off);

  knn_part_kernel<K / NCH><<<B * (K / QBLK) * NCH, QPB, 0, stream>>>(x, part);
  sor_value_kernel<NCH><<<B * 32, 256, 0, stream>>>(part, value, bsum);
  sor_thresh_kernel<<<1, 64, 0, stream>>>(bsum, thr);
  sor_mask_kernel<<<B * K / 256, 256, 0, stream>>>(x, value, thr, out);
}

extern "C" void kernel_launch(void* const* d_in, const int* in_sizes, int n_in,
                              void* d_out, int out_size, void* d_ws, size_t ws_size,
                              hipStream_t stream) {
  const float* x = (const float*)d_in[0];
  float* out = (float*)d_out;
  char* ws = (char*)d_ws;

  const size_t extra = (size_t)B * K * sizeof(float) + 4096;
  if (ws_size >= (size_t)B * K * 16 * 3 * sizeof(float) + extra) {
    run<16>(x, out, ws, stream);   // 1024 blocks, 8 KiB LDS
  } else if (ws_size >= (size_t)B * K * 8 * 3 * sizeof(float) + extra) {
    run<8>(x, out, ws, stream);    // 512 blocks, 16 KiB LDS
  } else {
    run<2>(x, out, ws, stream);    // 256 blocks, 64 KiB LDS
  }
}

// Round 4
// 80.912 us; speedup vs baseline: 2.3746x; 1.1629x over previous
//
#include <hip/hip_runtime.h>
#include <math.h>

// SOR defense: B=4, K=8192, 3D points. kNN k=2 (3 smallest incl. self).
// Outputs: masked_pc [4,8192,3] then mask [4,8192] (floats).

constexpr int B = 4;
constexpr int K = 8192;
constexpr int QPB = 256;         // threads per block
constexpr int QPT = 4;           // queries per thread
constexpr int QBLK = QPB * QPT;  // 1024 queries per block

#define BIG 3.0e38f

// Exact top-3 insert via med3: for sorted e0<=e1<=e2 and candidate d, the
// 3 smallest of {e0,e1,e2,d} sorted are {min(e0,d), med3(d,e0,e1),
// med3(d,e1,e2)}. Pure selection ops -> bit-identical to compare/swap chain,
// 3 independent VALU ops.
#define MINSERT(d, e0, e1, e2)                         \
  do {                                                 \
    const float n0_ = fminf((e0), (d));                \
    const float n1_ = __builtin_amdgcn_fmed3f((d), (e0), (e1)); \
    const float n2_ = __builtin_amdgcn_fmed3f((d), (e1), (e2)); \
    (e0) = n0_; (e1) = n1_; (e2) = n2_;                \
  } while (0)

// One (point, query) update. Distance expression textually identical to the
// validated R3 kernel -> identical rounding -> bit-identical values.
#define PQ_STEP(P, Q, PAR)                                             \
  do {                                                                 \
    const float dot_ = (qx[Q] * (P).x + qy[Q] * (P).y) + qz[Q] * (P).z; \
    const float d_ = (qn[Q] - 2.0f * dot_) + (P).w;                    \
    MINSERT(d_, e0[Q][PAR], e1[Q][PAR], e2[Q][PAR]);                   \
  } while (0)

template <int CHUNK>
__global__ __launch_bounds__(QPB) void knn_part_kernel(
    const float* __restrict__ x, float* __restrict__ part) {
  constexpr int NCH = K / CHUNK;
  const int bid   = blockIdx.x;
  const int chunk = bid % NCH;
  const int rest  = bid / NCH;
  const int kc    = rest % (K / QBLK);
  const int b     = rest / (K / QBLK);
  const int tid   = threadIdx.x;

  const float* xb = x + (size_t)b * K * 3;

  float qx[QPT], qy[QPT], qz[QPT], qn[QPT];
#pragma unroll
  for (int q = 0; q < QPT; ++q) {
    const int k = kc * QBLK + q * QPB + tid;
    qx[q] = xb[(size_t)k * 3 + 0];
    qy[q] = xb[(size_t)k * 3 + 1];
    qz[q] = xb[(size_t)k * 3 + 2];
    qn[q] = (qx[q] * qx[q] + qy[q] * qy[q]) + qz[q] * qz[q];
  }

  __shared__ float4 s[CHUNK];  // (x, y, z, ||p||^2)
  const int jbase = chunk * CHUNK;
  for (int i = tid; i < CHUNK; i += QPB) {
    const float px = xb[(size_t)(jbase + i) * 3 + 0];
    const float py = xb[(size_t)(jbase + i) * 3 + 1];
    const float pz = xb[(size_t)(jbase + i) * 3 + 2];
    s[i] = make_float4(px, py, pz, (px * px + py * py) + pz * pz);
  }
  __syncthreads();

  // Per query: two parity chains (j even / j odd), merged exactly at the end.
  float e0[QPT][2], e1[QPT][2], e2[QPT][2];
#pragma unroll
  for (int q = 0; q < QPT; ++q)
#pragma unroll
    for (int p = 0; p < 2; ++p) { e0[q][p] = BIG; e1[q][p] = BIG; e2[q][p] = BIG; }

  for (int j = 0; j < CHUNK; j += 4) {
    const float4 pA = s[j + 0];
    const float4 pB = s[j + 1];
    const float4 pC = s[j + 2];
    const float4 pD = s[j + 3];
#pragma unroll
    for (int q = 0; q < QPT; ++q) {
      PQ_STEP(pA, q, 0);
      PQ_STEP(pB, q, 1);
      PQ_STEP(pC, q, 0);
      PQ_STEP(pD, q, 1);
    }
  }

#pragma unroll
  for (int q = 0; q < QPT; ++q) {
    // merge odd-parity chain into even-parity chain (exact multiset top-3)
    MINSERT(e0[q][1], e0[q][0], e1[q][0], e2[q][0]);
    MINSERT(e1[q][1], e0[q][0], e1[q][0], e2[q][0]);
    MINSERT(e2[q][1], e0[q][0], e1[q][0], e2[q][0]);
    const int k = kc * QBLK + q * QPB + tid;
    float* pp = part + ((size_t)(b * K + k) * NCH + chunk) * 3;
    pp[0] = e0[q][0];
    pp[1] = e1[q][0];
    pp[2] = e2[q][0];
  }
}

// Stage 1: merge partials -> value[b,k]; per-block double sums.
template <int NCH>
__global__ __launch_bounds__(256) void sor_value_kernel(
    const float* __restrict__ part, float* __restrict__ value,
    double* __restrict__ bsum) {
  const int blk = blockIdx.x;  // b*32 + sub
  const int b   = blk >> 5;
  const int tid = threadIdx.x;
  const int k   = (blk & 31) * 256 + tid;

  const float* pp = part + (size_t)(b * K + k) * NCH * 3;
  float d0 = BIG, d1 = BIG, d2 = BIG;
#pragma unroll
  for (int t = 0; t < NCH * 3; ++t) {
    const float d = pp[t];
    MINSERT(d, d0, d1, d2);
  }
  const float v = 0.5f * (d1 + d2);  // drop self (d0), mean of 2 kNN
  value[b * K + k] = v;

  double s = (double)v, s2 = (double)v * (double)v;
  for (int off = 32; off > 0; off >>= 1) {
    s  += __shfl_down(s, off, 64);
    s2 += __shfl_down(s2, off, 64);
  }
  __shared__ double rs[4], rs2[4];
  const int wave = tid >> 6;
  if ((tid & 63) == 0) { rs[wave] = s; rs2[wave] = s2; }
  __syncthreads();
  if (tid == 0) {
    double S = 0.0, S2 = 0.0;
    for (int w = 0; w < 4; ++w) { S += rs[w]; S2 += rs2[w]; }  // fixed order
    bsum[blk * 2 + 0] = S;
    bsum[blk * 2 + 1] = S2;
  }
}

// Stage 2: threshold per batch (fixed order -> deterministic).
__global__ __launch_bounds__(64) void sor_thresh_kernel(
    const double* __restrict__ bsum, float* __restrict__ thr) {
  const int b = threadIdx.x;
  if (b < B) {
    double S = 0.0, S2 = 0.0;
    for (int w = 0; w < 32; ++w) {
      S  += bsum[(b * 32 + w) * 2 + 0];
      S2 += bsum[(b * 32 + w) * 2 + 1];
    }
    const double mean = S / (double)K;
    const double var  = (S2 - S * S / (double)K) / (double)(K - 1);
    thr[b] = (float)(mean + 1.1 * sqrt(var));
  }
}

// Stage 3: apply mask.
__global__ __launch_bounds__(256) void sor_mask_kernel(
    const float* __restrict__ x, const float* __restrict__ value,
    const float* __restrict__ thr, float* __restrict__ out) {
  const int g = blockIdx.x * 256 + threadIdx.x;  // b*K + k
  const int b = g / K;
  const float m = (value[g] <= thr[b]) ? 1.0f : 0.0f;
  out[(size_t)B * K * 3 + g] = m;
  const size_t base = (size_t)g * 3;
  out[base + 0] = x[base + 0] * m;
  out[base + 1] = x[base + 1] * m;
  out[base + 2] = x[base + 2] * m;
}

template <int NCH>
static void run(const float* x, float* out, char* ws, hipStream_t stream) {
  float* part = (float*)ws;
  size_t off = (size_t)B * K * NCH * 3 * sizeof(float);
  float* value = (float*)(ws + off);
  off += (size_t)B * K * sizeof(float);
  off = (off + 7) & ~(size_t)7;
  double* bsum = (double*)(ws + off);
  off += (size_t)B * 32 * 2 * sizeof(double);
  float* thr = (float*)(ws + off);

  knn_part_kernel<K / NCH><<<B * (K / QBLK) * NCH, QPB, 0, stream>>>(x, part);
  sor_value_kernel<NCH><<<B * 32, 256, 0, stream>>>(part, value, bsum);
  sor_thresh_kernel<<<1, 64, 0, stream>>>(bsum, thr);
  sor_mask_kernel<<<B * K / 256, 256, 0, stream>>>(x, value, thr, out);
}

extern "C" void kernel_launch(void* const* d_in, const int* in_sizes, int n_in,
                              void* d_out, int out_size, void* d_ws, size_t ws_size,
                              hipStream_t stream) {
  const float* x = (const float*)d_in[0];
  float* out = (float*)d_out;
  char* ws = (char*)d_ws;

  const size_t extra = (size_t)B * K * sizeof(float) + 4096;
  if (ws_size >= (size_t)B * K * 32 * 3 * sizeof(float) + extra) {
    run<32>(x, out, ws, stream);   // 1024 blocks, 4 KiB LDS
  } else if (ws_size >= (size_t)B * K * 16 * 3 * sizeof(float) + extra) {
    run<16>(x, out, ws, stream);   // 512 blocks, 8 KiB LDS
  } else if (ws_size >= (size_t)B * K * 8 * 3 * sizeof(float) + extra) {
    run<8>(x, out, ws, stream);    // 256 blocks, 16 KiB LDS
  } else {
    run<2>(x, out, ws, stream);    // 64 blocks, 64 KiB LDS
  }
}

// Round 5
// 75.168 us; speedup vs baseline: 2.5561x; 1.0764x over previous
//
#include <hip/hip_runtime.h>
#include <math.h>

// SOR defense: B=4, K=8192, 3D points. kNN k=2 (3 smallest incl. self).
// Outputs: masked_pc [4,8192,3] then mask [4,8192] (floats).

constexpr int B = 4;
constexpr int K = 8192;
constexpr int QPB = 256;         // threads per block
constexpr int QPT = 4;           // queries per thread
constexpr int QBLK = QPB * QPT;  // 1024 queries per block

#define BIG 3.0e38f

// Exact top-3 insert via med3: for sorted e0<=e1<=e2 and candidate d, the
// 3 smallest of {e0,e1,e2,d} sorted are {min(e0,d), med3(d,e0,e1),
// med3(d,e1,e2)}. Pure selection -> exact order statistics, 3 independent ops.
#define MINSERT(d, e0, e1, e2)                                  \
  do {                                                          \
    const float n0_ = fminf((e0), (d));                         \
    const float n1_ = __builtin_amdgcn_fmed3f((d), (e0), (e1)); \
    const float n2_ = __builtin_amdgcn_fmed3f((d), (e1), (e2)); \
    (e0) = n0_; (e1) = n1_; (e2) = n2_;                         \
  } while (0)

// One (point, query) update. Distance expression textually identical to the
// validated R3/R4 kernels -> identical rounding -> bit-identical values.
#define PQ_STEP(P, Q)                                                   \
  do {                                                                  \
    const float dot_ = (qx[Q] * (P).x + qy[Q] * (P).y) + qz[Q] * (P).z; \
    const float d_ = (qn[Q] - 2.0f * dot_) + (P).w;                     \
    MINSERT(d_, e0[Q], e1[Q], e2[Q]);                                   \
  } while (0)

template <int CHUNK>
__global__ __launch_bounds__(QPB, 4) void knn_part_kernel(
    const float* __restrict__ x, float* __restrict__ part) {
  constexpr int NCH = K / CHUNK;
  const int bid   = blockIdx.x;
  const int chunk = bid % NCH;
  const int rest  = bid / NCH;
  const int kc    = rest % (K / QBLK);
  const int b     = rest / (K / QBLK);
  const int tid   = threadIdx.x;

  const float* xb = x + (size_t)b * K * 3;

  float qx[QPT], qy[QPT], qz[QPT], qn[QPT];
#pragma unroll
  for (int q = 0; q < QPT; ++q) {
    const int k = kc * QBLK + q * QPB + tid;
    qx[q] = xb[(size_t)k * 3 + 0];
    qy[q] = xb[(size_t)k * 3 + 1];
    qz[q] = xb[(size_t)k * 3 + 2];
    qn[q] = (qx[q] * qx[q] + qy[q] * qy[q]) + qz[q] * qz[q];
  }

  __shared__ float4 s[CHUNK];  // (x, y, z, ||p||^2)
  const int jbase = chunk * CHUNK;
  for (int i = tid; i < CHUNK; i += QPB) {
    const float px = xb[(size_t)(jbase + i) * 3 + 0];
    const float py = xb[(size_t)(jbase + i) * 3 + 1];
    const float pz = xb[(size_t)(jbase + i) * 3 + 2];
    s[i] = make_float4(px, py, pz, (px * px + py * py) + pz * pz);
  }
  __syncthreads();

  // One top-3 chain per query. Same-chain dependent inserts are ~32
  // instructions apart (8 points x 4 queries interleave) -> latency hidden.
  float e0[QPT], e1[QPT], e2[QPT];
#pragma unroll
  for (int q = 0; q < QPT; ++q) { e0[q] = BIG; e1[q] = BIG; e2[q] = BIG; }

  for (int j = 0; j < CHUNK; j += 8) {
    float4 pts[8];
#pragma unroll
    for (int u = 0; u < 8; ++u) pts[u] = s[j + u];
#pragma unroll
    for (int u = 0; u < 8; ++u) {
#pragma unroll
      for (int q = 0; q < QPT; ++q) {
        PQ_STEP(pts[u], q);
      }
    }
  }

#pragma unroll
  for (int q = 0; q < QPT; ++q) {
    const int k = kc * QBLK + q * QPB + tid;
    float* pp = part + ((size_t)(b * K + k) * NCH + chunk) * 3;
    pp[0] = e0[q];
    pp[1] = e1[q];
    pp[2] = e2[q];
  }
}

// Stage 1: merge partials -> value[b,k]; per-block double sums.
template <int NCH>
__global__ __launch_bounds__(256) void sor_value_kernel(
    const float* __restrict__ part, float* __restrict__ value,
    double* __restrict__ bsum) {
  const int blk = blockIdx.x;  // b*32 + sub
  const int b   = blk >> 5;
  const int tid = threadIdx.x;
  const int k   = (blk & 31) * 256 + tid;

  const float* pp = part + (size_t)(b * K + k) * NCH * 3;
  float d0 = BIG, d1 = BIG, d2 = BIG;
#pragma unroll
  for (int t = 0; t < NCH * 3; ++t) {
    const float d = pp[t];
    MINSERT(d, d0, d1, d2);
  }
  const float v = 0.5f * (d1 + d2);  // drop self (d0), mean of 2 kNN
  value[b * K + k] = v;

  double s = (double)v, s2 = (double)v * (double)v;
  for (int off = 32; off > 0; off >>= 1) {
    s  += __shfl_down(s, off, 64);
    s2 += __shfl_down(s2, off, 64);
  }
  __shared__ double rs[4], rs2[4];
  const int wave = tid >> 6;
  if ((tid & 63) == 0) { rs[wave] = s; rs2[wave] = s2; }
  __syncthreads();
  if (tid == 0) {
    double S = 0.0, S2 = 0.0;
    for (int w = 0; w < 4; ++w) { S += rs[w]; S2 += rs2[w]; }  // fixed order
    bsum[blk * 2 + 0] = S;
    bsum[blk * 2 + 1] = S2;
  }
}

// Stage 2: threshold per batch (fixed order -> deterministic).
__global__ __launch_bounds__(64) void sor_thresh_kernel(
    const double* __restrict__ bsum, float* __restrict__ thr) {
  const int b = threadIdx.x;
  if (b < B) {
    double S = 0.0, S2 = 0.0;
    for (int w = 0; w < 32; ++w) {
      S  += bsum[(b * 32 + w) * 2 + 0];
      S2 += bsum[(b * 32 + w) * 2 + 1];
    }
    const double mean = S / (double)K;
    const double var  = (S2 - S * S / (double)K) / (double)(K - 1);
    thr[b] = (float)(mean + 1.1 * sqrt(var));
  }
}

// Stage 3: apply mask.
__global__ __launch_bounds__(256) void sor_mask_kernel(
    const float* __restrict__ x, const float* __restrict__ value,
    const float* __restrict__ thr, float* __restrict__ out) {
  const int g = blockIdx.x * 256 + threadIdx.x;  // b*K + k
  const int b = g / K;
  const float m = (value[g] <= thr[b]) ? 1.0f : 0.0f;
  out[(size_t)B * K * 3 + g] = m;
  const size_t base = (size_t)g * 3;
  out[base + 0] = x[base + 0] * m;
  out[base + 1] = x[base + 1] * m;
  out[base + 2] = x[base + 2] * m;
}

template <int NCH>
static void run(const float* x, float* out, char* ws, hipStream_t stream) {
  float* part = (float*)ws;
  size_t off = (size_t)B * K * NCH * 3 * sizeof(float);
  float* value = (float*)(ws + off);
  off += (size_t)B * K * sizeof(float);
  off = (off + 7) & ~(size_t)7;
  double* bsum = (double*)(ws + off);
  off += (size_t)B * 32 * 2 * sizeof(double);
  float* thr = (float*)(ws + off);

  knn_part_kernel<K / NCH><<<B * (K / QBLK) * NCH, QPB, 0, stream>>>(x, part);
  sor_value_kernel<NCH><<<B * 32, 256, 0, stream>>>(part, value, bsum);
  sor_thresh_kernel<<<1, 64, 0, stream>>>(bsum, thr);
  sor_mask_kernel<<<B * K / 256, 256, 0, stream>>>(x, value, thr, out);
}

extern "C" void kernel_launch(void* const* d_in, const int* in_sizes, int n_in,
                              void* d_out, int out_size, void* d_ws, size_t ws_size,
                              hipStream_t stream) {
  const float* x = (const float*)d_in[0];
  float* out = (float*)d_out;
  char* ws = (char*)d_ws;

  const size_t extra = (size_t)B * K * sizeof(float) + 4096;
  if (ws_size >= (size_t)B * K * 32 * 3 * sizeof(float) + extra) {
    run<32>(x, out, ws, stream);   // 1024 blocks, 4 KiB LDS
  } else if (ws_size >= (size_t)B * K * 16 * 3 * sizeof(float) + extra) {
    run<16>(x, out, ws, stream);   // 512 blocks, 8 KiB LDS
  } else if (ws_size >= (size_t)B * K * 8 * 3 * sizeof(float) + extra) {
    run<8>(x, out, ws, stream);    // 256 blocks, 16 KiB LDS
  } else {
    run<2>(x, out, ws, stream);    // 64 blocks, 64 KiB LDS
  }
}